// Round 11
// baseline (135.434 us; speedup 1.0000x reference)
//
#include <hip/hip_runtime.h>

#define NSEQ 4096
#define EDIM 1024

// Cross-dispatch intermediates in __device__ globals (round 10: the harness
// re-poisons d_ws unconditionally, but globals cost nothing and are clean).
// Every element is fully rewritten each iteration before any read.
__device__ float  g_pbx[4 * 64 * NSEQ];   // partial Bx [4 q][64 chain][4096 t]
__device__ float2 g_hp [64 * NSEQ];       // {h_loc, P_inc} [64 chain][4096 t]
__device__ float2 g_sum[64 * 16];         // {h_last, P_prod} [64 chain][16 chunk]

__device__ __forceinline__ void fma4(float4& a, float xv, const float4& b) {
    a.x = fmaf(xv, b.x, a.x);
    a.y = fmaf(xv, b.y, a.y);
    a.z = fmaf(xv, b.z, a.z);
    a.w = fmaf(xv, b.w, a.w);
}

// ---------------------------------------------------------------------------
// k1: partial Bx = x @ B_in over one e-quarter (256 e). Identical to the
// round-10 version EXCEPT the B operand path (single-variable experiment):
// B-quarter (16 KB) is staged into LDS once per block and read in the FMA
// loop as wave-uniform ds_read_b128 BROADCASTS instead of s_load_dwordx4.
// Rationale: hiding ~200cyc SMEM latency needs ~7 B-groups in flight x16
// SGPRs each — the ~102-SGPR file caps lookahead at ~3-4 groups, so the
// scalar path can't pipeline. The DS pipe has no such register-file cap and
// same-address b128 reads are conflict-free broadcasts.
// LDS: 16 KB (B) + 17.4 KB (red) = 33.8 KB <= 40 KB -> 4 blocks/CU kept.
// ---------------------------------------------------------------------------
__global__ __launch_bounds__(256, 4) void k1_bx(const float* __restrict__ x,
                                                const float* __restrict__ Bin) {
    __shared__ __align__(16) float sB[256 * 16];   // 16 KB: [e_local][s]
    __shared__ float red[4 * 64 * 17];             // 17.4 KB (reduction)
    const int tid  = threadIdx.x;
    const int lane = tid & 63;                                  // row
    const int wu   = __builtin_amdgcn_readfirstlane(tid) >> 6;  // wave id
    const int q    = blockIdx.x & 3;                            // e-quarter
    const int r0   = (blockIdx.x >> 2) * 64;                    // row base
    const int b    = r0 >> 12;
    const int n0   = r0 & 4095;

    const float4* xf4 = (const float4*)x;

    // stage B quarter into LDS (coalesced: 1024 float4, 4 per thread)
    {
        const float4* Bsrc = ((const float4*)Bin) + (size_t)q * 1024;
        float4* Bd = (float4*)sB;
#pragma unroll
        for (int k = 0; k < 4; k++) Bd[tid + 256 * k] = Bsrc[tid + 256 * k];
    }

    // this thread's x: row r0+lane, e-locals {c*64 + wu*16 + 0..15}, c=0..3
    float4 xr[16];
    const size_t rowb = (size_t)(r0 + lane) * 256 + q * 64 + wu * 4;
#pragma unroll
    for (int c = 0; c < 4; c++)
#pragma unroll
        for (int jj = 0; jj < 4; jj++)
            xr[c * 4 + jj] = xf4[rowb + c * 16 + jj];

    float acc[16];
#pragma unroll
    for (int s = 0; s < 16; s++) acc[s] = 0.f;

    __syncthreads();   // B staged

    const float4* Bl = (const float4*)sB;   // wave-uniform addresses
#pragma unroll
    for (int c = 0; c < 4; ++c) {
#pragma unroll
        for (int jj = 0; jj < 4; ++jj) {
            const float4 xq = xr[c * 4 + jj];
            const float xs[4] = {xq.x, xq.y, xq.z, xq.w};
#pragma unroll
            for (int m = 0; m < 4; ++m) {
                const int el = c * 64 + wu * 16 + jj * 4 + m;   // wave-uniform
                const float4 b0 = Bl[el * 4 + 0];   // ds_read_b128 broadcast
                const float4 b1 = Bl[el * 4 + 1];
                const float4 b2 = Bl[el * 4 + 2];
                const float4 b3 = Bl[el * 4 + 3];
                const float xv = xs[m];
                acc[0]  = fmaf(xv, b0.x, acc[0]);  acc[1]  = fmaf(xv, b0.y, acc[1]);
                acc[2]  = fmaf(xv, b0.z, acc[2]);  acc[3]  = fmaf(xv, b0.w, acc[3]);
                acc[4]  = fmaf(xv, b1.x, acc[4]);  acc[5]  = fmaf(xv, b1.y, acc[5]);
                acc[6]  = fmaf(xv, b1.z, acc[6]);  acc[7]  = fmaf(xv, b1.w, acc[7]);
                acc[8]  = fmaf(xv, b2.x, acc[8]);  acc[9]  = fmaf(xv, b2.y, acc[9]);
                acc[10] = fmaf(xv, b2.z, acc[10]); acc[11] = fmaf(xv, b2.w, acc[11]);
                acc[12] = fmaf(xv, b3.x, acc[12]); acc[13] = fmaf(xv, b3.y, acc[13]);
                acc[14] = fmaf(xv, b3.z, acc[14]); acc[15] = fmaf(xv, b3.w, acc[15]);
            }
        }
    }

    // cross-wave reduction: red[4 waves][64 rows][17] (separate buffer,
    // no aliasing with sB -> no extra barrier needed here)
    {
        const int rb = (wu * 64 + lane) * 17;
#pragma unroll
        for (int s = 0; s < 16; s++) red[rb + s] = acc[s];
    }
    __syncthreads();

#pragma unroll
    for (int p = 0; p < 4; p++) {
        const int o   = tid + 256 * p;
        const int s   = o >> 6;      // wave-uniform
        const int row = o & 63;
        const float v = red[(0 * 64 + row) * 17 + s] + red[(1 * 64 + row) * 17 + s] +
                        red[(2 * 64 + row) * 17 + s] + red[(3 * 64 + row) * 17 + s];
        g_pbx[(size_t)q * 262144u + (size_t)(b * 16 + s) * NSEQ + n0 + row] = v;
    }
}

// ---------------------------------------------------------------------------
// k2: sum 4 partial-Bx quarters, softplus -> decay, 256-wide chunk-local
// scan. 1024 blocks x 256 threads; block = (chain, 256-step chunk).
// (unchanged from round 10)
// ---------------------------------------------------------------------------
__global__ __launch_bounds__(256) void k2_scan(const float* __restrict__ A) {
    __shared__ float sP[4], sH[4];
    const int tid   = threadIdx.x;
    const int lane  = tid & 63;
    const int w     = tid >> 6;
    const int chain = blockIdx.x >> 4;
    const int chunk = blockIdx.x & 15;
    const int ss    = chain & 15;
    const int t     = chunk * 256 + tid;

    float bxv = 0.f;
#pragma unroll
    for (int q = 0; q < 4; q++)
        bxv += g_pbx[(size_t)q * 262144u + (size_t)chain * NSEQ + t];

    const float Ae = expf(A[ss]);
    const float sp = fmaxf(bxv, 0.f) + log1pf(expf(-fabsf(bxv)));
    const float de = expf(-Ae * sp);

    float Pi = de, hi = bxv;
#pragma unroll
    for (int off = 1; off < 64; off <<= 1) {
        float Pp = __shfl_up(Pi, off, 64);
        float hp = __shfl_up(hi, off, 64);
        if (lane >= off) { hi = fmaf(hp, Pi, hi); Pi *= Pp; }
    }
    if (lane == 63) { sP[w] = Pi; sH[w] = hi; }
    __syncthreads();
    float Hw = 0.f, Pw = 1.f;
    for (int qq = 0; qq < w; qq++) { Hw = fmaf(Hw, sP[qq], sH[qq]); Pw *= sP[qq]; }

    const float hloc = fmaf(Hw, Pi, hi);
    const float pinc = Pw * Pi;
    g_hp[(size_t)chain * NSEQ + t] = make_float2(hloc, pinc);
    if (tid == 255)
        g_sum[chain * 16 + chunk] = make_float2(hloc, pinc);
}

// ---------------------------------------------------------------------------
// k3: carry-in H from <=15 chunk summaries, h = fma(P_inc, H, h_loc) into a
// 16x20 LDS tile (b128 broadcast reads), then y = h@C (+ x*D slow path).
// (unchanged from round 10)
// ---------------------------------------------------------------------------
__global__ __launch_bounds__(256) void k3_out(const float* __restrict__ x,
                                              const float* __restrict__ C,
                                              const float* __restrict__ D,
                                              float* __restrict__ out) {
    __shared__ __align__(16) float sh[16 * 20];
    const int tid = threadIdx.x;
    const int blk = blockIdx.x;
    const int tc  = blk & 255;
    const int b   = blk >> 8;
    const int t0  = tc * 16;

    {
        const int s  = tid >> 4;
        const int tt = tid & 15;
        const int chain = b * 16 + s;
        const int t = t0 + tt;
        const int chunk = t >> 8;
        float H = 0.f;
        for (int c = 0; c < chunk; ++c) {
            const float2 su = g_sum[chain * 16 + c];
            H = fmaf(H, su.y, su.x);
        }
        const float2 hp = g_hp[(size_t)chain * NSEQ + t];
        sh[tt * 20 + s] = fmaf(hp.y, H, hp.x);
    }

    const float4* C4 = (const float4*)C;
    float4 creg[16];
#pragma unroll
    for (int s = 0; s < 16; s++) creg[s] = C4[s * 256 + tid];
    const float4 dreg = ((const float4*)D)[tid];
    const bool needX = __any((dreg.x != 0.f) | (dreg.y != 0.f) |
                             (dreg.z != 0.f) | (dreg.w != 0.f));
    __syncthreads();

    const float4* x4 = (const float4*)x;
    float4* o4 = (float4*)out;
    const size_t rowbase = ((size_t)b * NSEQ + t0) * 256;

    if (needX) {
#pragma unroll 4
        for (int tt = 0; tt < 16; tt++) {
            float4 xv = x4[rowbase + tt * 256 + tid];
            float4 y;
            y.x = xv.x * dreg.x; y.y = xv.y * dreg.y;
            y.z = xv.z * dreg.z; y.w = xv.w * dreg.w;
#pragma unroll
            for (int g = 0; g < 4; g++) {
                const float4 h4 = *(const float4*)&sh[tt * 20 + g * 4];
                fma4(y, h4.x, creg[g * 4 + 0]);
                fma4(y, h4.y, creg[g * 4 + 1]);
                fma4(y, h4.z, creg[g * 4 + 2]);
                fma4(y, h4.w, creg[g * 4 + 3]);
            }
            o4[rowbase + tt * 256 + tid] = y;
        }
    } else {
#pragma unroll 4
        for (int tt = 0; tt < 16; tt++) {
            float4 y = make_float4(0.f, 0.f, 0.f, 0.f);
#pragma unroll
            for (int g = 0; g < 4; g++) {
                const float4 h4 = *(const float4*)&sh[tt * 20 + g * 4];
                fma4(y, h4.x, creg[g * 4 + 0]);
                fma4(y, h4.y, creg[g * 4 + 1]);
                fma4(y, h4.z, creg[g * 4 + 2]);
                fma4(y, h4.w, creg[g * 4 + 3]);
            }
            o4[rowbase + tt * 256 + tid] = y;
        }
    }
}

extern "C" void kernel_launch(void* const* d_in, const int* in_sizes, int n_in,
                              void* d_out, int out_size, void* d_ws, size_t ws_size,
                              hipStream_t stream) {
    const float* x   = (const float*)d_in[0];
    const float* A   = (const float*)d_in[1];
    const float* Bin = (const float*)d_in[2];
    const float* C   = (const float*)d_in[3];
    const float* D   = (const float*)d_in[4];
    float* out = (float*)d_out;
    (void)d_ws; (void)ws_size;

    hipLaunchKernelGGL(k1_bx,   dim3(1024), dim3(256), 0, stream, x, Bin);
    hipLaunchKernelGGL(k2_scan, dim3(1024), dim3(256), 0, stream, A);
    hipLaunchKernelGGL(k3_out,  dim3(1024), dim3(256), 0, stream, x, C, D, out);
}